// Round 1
// 307.702 us; speedup vs baseline: 1.0277x; 1.0277x over previous
//
#include <hip/hip_runtime.h>

// WARP loss: B=4096 rows, Y=10000 labels, T=128 negative-candidate trials.
// input [B,Y] f32, target [B,Y] f32 (exactly one-hot), neg_candidates [B,T] i32.
// out[0] = sum over rows of log((Y-1)/num_trials) * (1 - s_pos + s_neg),
// where num_trials = 1 + first t with 1 + s_neg_t - s_pos >= 0 (0 if none).
//
// Two-phase structure:
//   Phase 1: pure streaming scan of target (uint4, 16B/lane, grid-stride,
//            no barriers). Finder thread writes spos[row] = input[flat_idx].
//            Also zeroes out[0] (replaces hipMemsetAsync dispatch).
//   Phase 2: one wave per row; 2 candidates/lane; ballot+ffs first-accept;
//            shfl for s_neg; LDS-accumulate; 1 atomic per block.

constexpr int Yc = 10000;
constexpr int Tc = 128;

__global__ __launch_bounds__(256) void find_pos_kernel(
        const float* __restrict__ input,
        const float* __restrict__ target,
        float* __restrict__ spos,          // [B] workspace
        float* __restrict__ out,
        int n4) {                          // B * Y / 4
    const int gid = blockIdx.x * 256 + threadIdx.x;
    if (gid == 0) out[0] = 0.0f;           // kernel boundary orders this vs phase 2
    const uint4* t4 = reinterpret_cast<const uint4*>(target);
    const int stride = gridDim.x * 256;
    #pragma unroll 4
    for (int i = gid; i < n4; i += stride) {
        uint4 v = t4[i];
        if (v.x | v.y | v.z | v.w) {       // 1.0f = 0x3F800000; taken ~4096/10.24M
            int k   = v.x ? 0 : (v.y ? 1 : (v.z ? 2 : 3));
            int idx = 4 * i + k;
            int row = idx / Yc;            // magic-mul; rare path
            spos[row] = input[idx];        // s_pos = input at the SAME flat index
        }
    }
}

__global__ __launch_bounds__(256) void warp_loss2_kernel(
        const float* __restrict__ input,
        const int*   __restrict__ neg,
        const float* __restrict__ spos,
        float* __restrict__ out,
        int B) {
    const int wave = threadIdx.x >> 6;     // 4 waves -> 4 rows per block
    const int lane = threadIdx.x & 63;
    const int row  = blockIdx.x * 4 + wave;

    __shared__ float sacc;
    if (threadIdx.x == 0) sacc = 0.0f;
    __syncthreads();

    if (row < B) {
        const float s_pos = spos[row];
        const int*  nrow  = neg + row * Tc;
        const int   c0 = nrow[lane];
        const int   c1 = nrow[lane + 64];
        const float* irow = input + (size_t)row * Yc;
        const float s0 = irow[c0];
        const float s1 = irow[c1];

        const unsigned long long b0 = __ballot(1.0f + s0 - s_pos >= 0.0f);
        const unsigned long long b1 = __ballot(1.0f + s1 - s_pos >= 0.0f);

        int   first = -1;
        float s_neg = 0.0f;
        if (b0) {
            first = __ffsll((unsigned long long)b0) - 1;          // min t in [0,64)
            s_neg = __shfl(s0, first);
        } else if (b1) {
            first = 64 + __ffsll((unsigned long long)b1) - 1;     // min t in [64,128)
            s_neg = __shfl(s1, first - 64);
        }
        if (lane == 0 && first >= 0) {
            const int   nt = first + 1;
            const float L  = logf((float)((Yc - 1) / nt));        // floor-div then log
            atomicAdd(&sacc, L * (1.0f - s_pos + s_neg));
        }
    }
    __syncthreads();
    if (threadIdx.x == 0) atomicAdd(out, sacc);
}

extern "C" void kernel_launch(void* const* d_in, const int* in_sizes, int n_in,
                              void* d_out, int out_size, void* d_ws, size_t ws_size,
                              hipStream_t stream) {
    const float* input  = (const float*)d_in[0];
    const float* target = (const float*)d_in[1];
    const int*   neg    = (const int*)d_in[2];
    float* out  = (float*)d_out;
    float* spos = (float*)d_ws;            // B floats = 16 KB

    const int B  = in_sizes[2] / Tc;       // 4096
    const int n4 = B * (Yc / 4);           // 10,240,000 uint4

    // Phase 1: streaming scan. 2048 blocks x 256 thr = 8 blocks/CU, ~19.5 uint4/thr.
    find_pos_kernel<<<2048, 256, 0, stream>>>(input, target, spos, out, n4);
    // Phase 2: one wave per row.
    warp_loss2_kernel<<<(B + 3) / 4, 256, 0, stream>>>(input, neg, spos, out, B);
}

// Round 3
// 293.200 us; speedup vs baseline: 1.0785x; 1.0495x over previous
//
#include <hip/hip_runtime.h>

// WARP loss: B=4096 rows, Y=10000 labels, T=128 negative-candidate trials.
// input [B,Y] f32, target [B,Y] f32 (one-hot), neg_candidates [B,T] i32.
// out[0] = sum over rows of log((Y-1)/num_trials) * (1 - s_pos + s_neg),
// num_trials = 1 + first t with 1 + s_neg_t - s_pos >= 0 (0 contribution if none).
//
// One wave per row, fused:
//   - prefetch neg indices + the two candidate gathers (independent of s_pos,
//     they land under the scan)
//   - scan target row in wave-groups, depth-4 software pipeline,
//     __any() early exit (expected ~54% of row read)
//   - dependent tail: one s_pos gather, ballots, shfl, per-block partial
//   - 1-block reduce kernel sums 1024 partials into out[0] (plain store
//     overwrites harness poison; no memset, no global atomics).

constexpr int Yc = 10000;
constexpr int Tc = 128;
constexpr int R4 = 2500;   // uint4 per row (40000 B, 16B-aligned per row)
constexpr int NG = 40;     // ceil(R4 / 64) wave-groups per row

__global__ __launch_bounds__(256) void warp_fused_kernel(
        const float* __restrict__ input,
        const float* __restrict__ target,
        const int*   __restrict__ neg,
        float* __restrict__ partial,
        int B) {
    const int wave = threadIdx.x >> 6;
    const int lane = threadIdx.x & 63;
    const int row  = blockIdx.x * 4 + wave;

    __shared__ float sacc[4];

    float contrib = 0.0f;
    if (row < B) {
        const int*   nrow = neg + row * Tc;
        const float* irow = input + (size_t)row * Yc;

        // ---- prefetch candidates; gathers fly during the scan ----
        const int   c0 = nrow[lane];
        const int   c1 = nrow[lane + 64];
        const float s0 = irow[c0];
        const float s1 = irow[c1];

        // ---- scan for the one-hot position, depth-4 pipeline + early exit ----
        const uint4* trow = reinterpret_cast<const uint4*>(target + (size_t)row * Yc);
        auto LD = [&](int j) -> uint4 {
            int idx = j * 64 + lane;
            return trow[idx < R4 ? idx : R4 - 1];   // clamp: harmless re-read
        };
        auto CAND = [&](int g, const uint4& v) -> int {
            int idx = g * 64 + lane;
            if (idx >= R4) idx = R4 - 1;
            int sub = v.x ? 0 : (v.y ? 1 : (v.z ? 2 : 3));
            return 4 * idx + sub;
        };

        uint4 a = LD(0), b = LD(1), c = LD(2), d = LD(3);
        int posIdx = -1;
        for (int j = 0; j < NG; j += 4) {
            const unsigned nza = a.x | a.y | a.z | a.w;
            const unsigned nzb = b.x | b.y | b.z | b.w;
            const unsigned nzc = c.x | c.y | c.z | c.w;
            const unsigned nzd = d.x | d.y | d.z | d.w;
            if (__any((nza | nzb | nzc | nzd) != 0)) {   // wave-uniform branch
                int mine = 0x7fffffff;
                if (nza) mine = min(mine, CAND(j + 0, a));
                if (nzb) mine = min(mine, CAND(j + 1, b));
                if (nzc) mine = min(mine, CAND(j + 2, c));
                if (nzd) mine = min(mine, CAND(j + 3, d));
                #pragma unroll
                for (int off = 32; off; off >>= 1)
                    mine = min(mine, __shfl_xor(mine, off));
                posIdx = mine;                            // earliest element index
                break;
            }
            a = LD(j + 4); b = LD(j + 5); c = LD(j + 6); d = LD(j + 7);
        }

        // ---- dependent tail: s_pos gather, first-accept, loss ----
        float s_pos = 0.0f;
        if (posIdx >= 0) s_pos = irow[posIdx];

        const unsigned long long b0 = __ballot(1.0f + s0 - s_pos >= 0.0f);
        const unsigned long long b1 = __ballot(1.0f + s1 - s_pos >= 0.0f);
        int   first = -1;
        float s_neg = 0.0f;
        if (b0) {
            first = __ffsll(b0) - 1;
            s_neg = __shfl(s0, first);
        } else if (b1) {
            first = 64 + __ffsll(b1) - 1;
            s_neg = __shfl(s1, first - 64);
        }
        if (posIdx >= 0 && first >= 0) {
            const int   nt = first + 1;
            const float L  = logf((float)((Yc - 1) / nt));  // floor-div then log
            contrib = L * (1.0f - s_pos + s_neg);
        }
    }

    if (lane == 0) sacc[wave] = contrib;   // contrib is wave-uniform
    __syncthreads();
    if (threadIdx.x == 0)
        partial[blockIdx.x] = sacc[0] + sacc[1] + sacc[2] + sacc[3];
}

__global__ __launch_bounds__(256) void reduce_partials(
        const float* __restrict__ partial,
        float* __restrict__ out, int n) {
    float s = 0.0f;
    for (int i = threadIdx.x; i < n; i += 256) s += partial[i];
    #pragma unroll
    for (int off = 32; off; off >>= 1) s += __shfl_down(s, off);
    __shared__ float ws[4];
    if ((threadIdx.x & 63) == 0) ws[threadIdx.x >> 6] = s;
    __syncthreads();
    if (threadIdx.x == 0) out[0] = ws[0] + ws[1] + ws[2] + ws[3];
}

extern "C" void kernel_launch(void* const* d_in, const int* in_sizes, int n_in,
                              void* d_out, int out_size, void* d_ws, size_t ws_size,
                              hipStream_t stream) {
    const float* input  = (const float*)d_in[0];
    const float* target = (const float*)d_in[1];
    const int*   neg    = (const int*)d_in[2];
    float* out     = (float*)d_out;
    float* partial = (float*)d_ws;             // nblk floats

    const int B    = in_sizes[2] / Tc;         // 4096
    const int nblk = (B + 3) / 4;              // 1024 blocks, 1 wave per row

    warp_fused_kernel<<<nblk, 256, 0, stream>>>(input, target, neg, partial, B);
    reduce_partials<<<1, 256, 0, stream>>>(partial, out, nblk);
}